// Round 2
// baseline (312.901 us; speedup 1.0000x reference)
//
#include <hip/hip_runtime.h>

// RoIAlign: features (B=4, C=256, H=200, W=200) f32, rois (R,5) f32,
// out (R, C, 7, 7) f32.  SCALE=0.25, AH=AW=7, legacy (x2-x1+1) semantics.
//
// Locality plan:
//  - 8 channel-groups of 32ch, block id = j*8 + g so XCD g (round-robin
//    dispatch heuristic) only touches channels [32g,32g+32): per-XCD feature
//    footprint 20.5 MB instead of 164 MB.
//  - ROIs processed in batch-sorted order (perm) so the live per-XCD feature
//    set is 32 planes x 160KB = 5MB ~ L2; output written via nontemporal
//    stores to keep L2 for features.

#define C_     256
#define H_     200
#define W_     200
#define NBIN   49     // 7*7
#define SCALE_ 0.25f
#define CGRP   32     // channels per XCD group
#define NGRP   8
#define PER_ROI_GRP (CGRP * NBIN)   // 1568 work items per (roi, group)

// ---------------- kernel 0: batch-stable sort permutation ------------------
// perm[rank] = roi index, ranks ordered by (batch, original index).
__global__ __launch_bounds__(256) void roi_sortperm(
        const float* __restrict__ rois, int* __restrict__ perm, int R) {
    int t = blockIdx.x * 256 + threadIdx.x;
    if (t >= R) return;
    int bt = (int)rois[t * 5];
    int rank = 0;
    for (int i = 0; i < R; ++i) {
        int bi = (int)rois[i * 5];
        rank += (bi < bt) || (bi == bt && i < t);
    }
    perm[rank] = t;
}

// ---------------- kernel 1: per-(roi,bin) geometry table -------------------
// table[i] = { hr, wr, as_float(h0 | w0<<8 | b<<16 | valid<<18), 0 }
__global__ __launch_bounds__(256) void roi_precompute(
        const float* __restrict__ rois, float4* __restrict__ table, int nbins) {
    int i = blockIdx.x * 256 + threadIdx.x;
    if (i >= nbins) return;
    int r   = i / NBIN;
    int bin = i - r * NBIN;
    int ph  = bin / 7;
    int pw  = bin - ph * 7;

    float bf = rois[r * 5 + 0];
    float x1 = rois[r * 5 + 1] * SCALE_;
    float y1 = rois[r * 5 + 2] * SCALE_;
    float x2 = rois[r * 5 + 3] * SCALE_;
    float y2 = rois[r * 5 + 4] * SCALE_;

    float roi_w = fmaxf(x2 - x1 + 1.0f, 0.0f);
    float roi_h = fmaxf(y2 - y1 + 1.0f, 0.0f);
    float bin_h = roi_h / 6.0f;   // AH-1
    float bin_w = roi_w / 6.0f;   // AW-1

    float h = y1 + (float)ph * bin_h;
    float w = x1 + (float)pw * bin_w;

    bool valid = (h >= 0.0f) && (h < (float)H_) && (w >= 0.0f) && (w < (float)W_);

    float h0f = fmaxf(fminf(floorf(h), (float)(H_ - 2)), 0.0f);
    float w0f = fmaxf(fminf(floorf(w), (float)(W_ - 2)), 0.0f);
    int h0 = (int)h0f;
    int w0 = (int)w0f;
    float hr = h - h0f;
    float wr = w - w0f;
    int b = (int)bf;

    int packed = h0 | (w0 << 8) | (b << 16) | ((valid ? 1 : 0) << 18);
    table[i] = make_float4(hr, wr, __int_as_float(packed), 0.0f);
}

// ---------------- kernel 2: main gather -------------------------------------
// bid = j*8 + g ; group g covers channels [g*32, g*32+32).
// Work item within group: w = (pos*32 + ci)*49 + bin, pos = batch-sorted roi.
__global__ __launch_bounds__(256) void roi_main(
        const float* __restrict__ feat, const float4* __restrict__ table,
        const int* __restrict__ perm, float* __restrict__ out, int R) {
    int bid = blockIdx.x;
    int g   = bid & (NGRP - 1);
    int j   = bid >> 3;
    int w   = j * 256 + threadIdx.x;

    int pos = w / PER_ROI_GRP;
    if (pos >= R) return;
    int rem = w - pos * PER_ROI_GRP;
    int ci  = rem / NBIN;
    int bin = rem - ci * NBIN;

    int r = perm[pos];
    int c = g * CGRP + ci;

    float4 t   = table[r * NBIN + bin];
    int packed = __float_as_int(t.z);
    int h0 = packed & 255;
    int w0 = (packed >> 8) & 255;
    int b  = (packed >> 16) & 3;
    float valid = (float)((packed >> 18) & 1);

    const float* p = feat + ((size_t)(b * C_ + c)) * (size_t)(H_ * W_)
                          + (size_t)(h0 * W_ + w0);
    float v00 = p[0];
    float v01 = p[1];
    float v10 = p[W_];
    float v11 = p[W_ + 1];

    float hr = t.x, wr = t.y;
    float top = fmaf(wr, v01 - v00, v00);
    float bot = fmaf(wr, v11 - v10, v10);
    float val = fmaf(hr, bot - top, top);

    int oidx = (r * C_ + c) * NBIN + bin;
    __builtin_nontemporal_store(val * valid, &out[oidx]);
}

// ---------------- fallback: fused (no workspace) ----------------------------
__global__ __launch_bounds__(256) void roi_fused(
        const float* __restrict__ feat, const float* __restrict__ rois,
        float* __restrict__ out, int total) {
    int idx = blockIdx.x * 256 + threadIdx.x;
    if (idx >= total) return;

    unsigned u   = (unsigned)idx;
    unsigned bin = u % (unsigned)NBIN;
    unsigned rc  = u / (unsigned)NBIN;
    unsigned c   = rc & 255u;
    unsigned r   = rc >> 8;
    int ph = bin / 7;
    int pw = bin - ph * 7;

    float bf = rois[r * 5 + 0];
    float x1 = rois[r * 5 + 1] * SCALE_;
    float y1 = rois[r * 5 + 2] * SCALE_;
    float x2 = rois[r * 5 + 3] * SCALE_;
    float y2 = rois[r * 5 + 4] * SCALE_;

    float roi_w = fmaxf(x2 - x1 + 1.0f, 0.0f);
    float roi_h = fmaxf(y2 - y1 + 1.0f, 0.0f);
    float h = y1 + (float)ph * (roi_h / 6.0f);
    float w = x1 + (float)pw * (roi_w / 6.0f);

    float valid = ((h >= 0.0f) && (h < (float)H_) && (w >= 0.0f) && (w < (float)W_))
                      ? 1.0f : 0.0f;

    float h0f = fmaxf(fminf(floorf(h), (float)(H_ - 2)), 0.0f);
    float w0f = fmaxf(fminf(floorf(w), (float)(W_ - 2)), 0.0f);
    int h0 = (int)h0f;
    int w0 = (int)w0f;
    float hr = h - h0f;
    float wr = w - w0f;
    int b = (int)bf;

    const float* p = feat + ((size_t)(b * C_ + (int)c)) * (size_t)(H_ * W_)
                          + (size_t)(h0 * W_ + w0);
    float v00 = p[0];
    float v01 = p[1];
    float v10 = p[W_];
    float v11 = p[W_ + 1];

    float top = fmaf(wr, v01 - v00, v00);
    float bot = fmaf(wr, v11 - v10, v10);
    float val = fmaf(hr, bot - top, top);

    out[idx] = val * valid;
}

extern "C" void kernel_launch(void* const* d_in, const int* in_sizes, int n_in,
                              void* d_out, int out_size, void* d_ws, size_t ws_size,
                              hipStream_t stream) {
    const float* feat = (const float*)d_in[0];
    const float* rois = (const float*)d_in[1];
    float* out = (float*)d_out;

    int R     = in_sizes[1] / 5;
    int nbins = R * NBIN;
    int total = R * C_ * NBIN;   // == out_size

    // workspace layout: perm (R ints), then 16B-aligned table (R*49 float4)
    size_t perm_bytes  = ((size_t)R * sizeof(int) + 15) & ~(size_t)15;
    size_t table_bytes = (size_t)nbins * sizeof(float4);

    if (perm_bytes + table_bytes <= ws_size) {
        int*    perm  = (int*)d_ws;
        float4* table = (float4*)((char*)d_ws + perm_bytes);

        roi_sortperm<<<(R + 255) / 256, 256, 0, stream>>>(rois, perm, R);
        roi_precompute<<<(nbins + 255) / 256, 256, 0, stream>>>(rois, table, nbins);

        int workPerGrp  = R * PER_ROI_GRP;            // R*1568
        int blocksPerGrp = (workPerGrp + 255) / 256;
        roi_main<<<blocksPerGrp * NGRP, 256, 0, stream>>>(feat, table, perm, out, R);
    } else {
        roi_fused<<<(total + 255) / 256, 256, 0, stream>>>(feat, rois, out, total);
    }
}

// Round 3
// 106.766 us; speedup vs baseline: 2.9307x; 2.9307x over previous
//
#include <hip/hip_runtime.h>

// RoIAlign: features (B=4, C=256, H=200, W=200) f32, rois (R,5) f32,
// out (R, C, 7, 7) f32.  SCALE=0.25, AH=AW=7, legacy (x2-x1+1) semantics.
//
// Locality plan:
//  - 8 channel-groups of 32ch, block id = j*8 + g so XCD g (round-robin
//    dispatch heuristic) only touches channels [32g,32g+32): per-XCD feature
//    footprint 20.5 MB instead of 164 MB.
//  - ROIs processed batch-grouped (perm from an O(R) counting sort) so the
//    live per-XCD feature set is 32 planes x 160KB = 5MB ~ L2 size.
//  - Output written once via nontemporal stores (keep L2 for features).

#define C_     256
#define H_     200
#define W_     200
#define NBIN   49     // 7*7
#define SCALE_ 0.25f
#define CGRP   32     // channels per XCD group
#define NGRP   8
#define PER_ROI_GRP (CGRP * NBIN)   // 1568 work items per (roi, group)
#define NBATCH 8      // >= actual B (4); batch ids are small ints

// ---------------- kernel 0: batch-grouping permutation (counting sort) -----
// Single block. Order within a batch is arbitrary (atomics) — output values
// do not depend on processing order, so d_out stays deterministic.
__global__ __launch_bounds__(1024) void roi_countsort(
        const float* __restrict__ rois, int* __restrict__ perm, int R) {
    __shared__ int cnt[NBATCH];
    __shared__ int off[NBATCH];
    int t = threadIdx.x;
    if (t < NBATCH) cnt[t] = 0;
    __syncthreads();
    for (int i = t; i < R; i += 1024) {
        int b = (int)rois[(size_t)i * 5];
        atomicAdd(&cnt[b & (NBATCH - 1)], 1);
    }
    __syncthreads();
    if (t == 0) {
        int s = 0;
        for (int b = 0; b < NBATCH; ++b) { off[b] = s; s += cnt[b]; }
    }
    __syncthreads();
    for (int i = t; i < R; i += 1024) {
        int b = (int)rois[(size_t)i * 5];
        int pos = atomicAdd(&off[b & (NBATCH - 1)], 1);
        perm[pos] = i;
    }
}

// ---------------- kernel 1: per-(roi,bin) geometry table -------------------
// table[i] = { hr, wr, as_float(h0 | w0<<8 | b<<16 | valid<<18), 0 }
__global__ __launch_bounds__(256) void roi_precompute(
        const float* __restrict__ rois, float4* __restrict__ table, int nbins) {
    int i = blockIdx.x * 256 + threadIdx.x;
    if (i >= nbins) return;
    int r   = i / NBIN;
    int bin = i - r * NBIN;
    int ph  = bin / 7;
    int pw  = bin - ph * 7;

    float bf = rois[r * 5 + 0];
    float x1 = rois[r * 5 + 1] * SCALE_;
    float y1 = rois[r * 5 + 2] * SCALE_;
    float x2 = rois[r * 5 + 3] * SCALE_;
    float y2 = rois[r * 5 + 4] * SCALE_;

    float roi_w = fmaxf(x2 - x1 + 1.0f, 0.0f);
    float roi_h = fmaxf(y2 - y1 + 1.0f, 0.0f);
    float bin_h = roi_h / 6.0f;   // AH-1
    float bin_w = roi_w / 6.0f;   // AW-1

    float h = y1 + (float)ph * bin_h;
    float w = x1 + (float)pw * bin_w;

    bool valid = (h >= 0.0f) && (h < (float)H_) && (w >= 0.0f) && (w < (float)W_);

    float h0f = fmaxf(fminf(floorf(h), (float)(H_ - 2)), 0.0f);
    float w0f = fmaxf(fminf(floorf(w), (float)(W_ - 2)), 0.0f);
    int h0 = (int)h0f;
    int w0 = (int)w0f;
    float hr = h - h0f;
    float wr = w - w0f;
    int b = (int)bf;

    int packed = h0 | (w0 << 8) | (b << 16) | ((valid ? 1 : 0) << 18);
    table[i] = make_float4(hr, wr, __int_as_float(packed), 0.0f);
}

// ---------------- kernel 2: main gather -------------------------------------
// bid = j*8 + g ; group g covers channels [g*32, g*32+32).
// Work item within group: w = (pos*32 + ci)*49 + bin, pos = batch-sorted roi.
__global__ __launch_bounds__(256) void roi_main(
        const float* __restrict__ feat, const float4* __restrict__ table,
        const int* __restrict__ perm, float* __restrict__ out, int R) {
    int bid = blockIdx.x;
    int g   = bid & (NGRP - 1);
    int j   = bid >> 3;
    int w   = j * 256 + threadIdx.x;

    int pos = w / PER_ROI_GRP;
    if (pos >= R) return;
    int rem = w - pos * PER_ROI_GRP;
    int ci  = rem / NBIN;
    int bin = rem - ci * NBIN;

    int r = perm[pos];
    int c = g * CGRP + ci;

    float4 t   = table[r * NBIN + bin];
    int packed = __float_as_int(t.z);
    int h0 = packed & 255;
    int w0 = (packed >> 8) & 255;
    int b  = (packed >> 16) & 3;
    float valid = (float)((packed >> 18) & 1);

    const float* p = feat + ((size_t)(b * C_ + c)) * (size_t)(H_ * W_)
                          + (size_t)(h0 * W_ + w0);
    float v00 = p[0];
    float v01 = p[1];
    float v10 = p[W_];
    float v11 = p[W_ + 1];

    float hr = t.x, wr = t.y;
    float top = fmaf(wr, v01 - v00, v00);
    float bot = fmaf(wr, v11 - v10, v10);
    float val = fmaf(hr, bot - top, top);

    int oidx = (r * C_ + c) * NBIN + bin;
    __builtin_nontemporal_store(val * valid, &out[oidx]);
}

// ---------------- fallback: fused (no workspace) ----------------------------
__global__ __launch_bounds__(256) void roi_fused(
        const float* __restrict__ feat, const float* __restrict__ rois,
        float* __restrict__ out, int total) {
    int idx = blockIdx.x * 256 + threadIdx.x;
    if (idx >= total) return;

    unsigned u   = (unsigned)idx;
    unsigned bin = u % (unsigned)NBIN;
    unsigned rc  = u / (unsigned)NBIN;
    unsigned c   = rc & 255u;
    unsigned r   = rc >> 8;
    int ph = bin / 7;
    int pw = bin - ph * 7;

    float bf = rois[r * 5 + 0];
    float x1 = rois[r * 5 + 1] * SCALE_;
    float y1 = rois[r * 5 + 2] * SCALE_;
    float x2 = rois[r * 5 + 3] * SCALE_;
    float y2 = rois[r * 5 + 4] * SCALE_;

    float roi_w = fmaxf(x2 - x1 + 1.0f, 0.0f);
    float roi_h = fmaxf(y2 - y1 + 1.0f, 0.0f);
    float h = y1 + (float)ph * (roi_h / 6.0f);
    float w = x1 + (float)pw * (roi_w / 6.0f);

    float valid = ((h >= 0.0f) && (h < (float)H_) && (w >= 0.0f) && (w < (float)W_))
                      ? 1.0f : 0.0f;

    float h0f = fmaxf(fminf(floorf(h), (float)(H_ - 2)), 0.0f);
    float w0f = fmaxf(fminf(floorf(w), (float)(W_ - 2)), 0.0f);
    int h0 = (int)h0f;
    int w0 = (int)w0f;
    float hr = h - h0f;
    float wr = w - w0f;
    int b = (int)bf;

    const float* p = feat + ((size_t)(b * C_ + (int)c)) * (size_t)(H_ * W_)
                          + (size_t)(h0 * W_ + w0);
    float v00 = p[0];
    float v01 = p[1];
    float v10 = p[W_];
    float v11 = p[W_ + 1];

    float top = fmaf(wr, v01 - v00, v00);
    float bot = fmaf(wr, v11 - v10, v10);
    float val = fmaf(hr, bot - top, top);

    out[idx] = val * valid;
}

extern "C" void kernel_launch(void* const* d_in, const int* in_sizes, int n_in,
                              void* d_out, int out_size, void* d_ws, size_t ws_size,
                              hipStream_t stream) {
    const float* feat = (const float*)d_in[0];
    const float* rois = (const float*)d_in[1];
    float* out = (float*)d_out;

    int R     = in_sizes[1] / 5;
    int nbins = R * NBIN;
    int total = R * C_ * NBIN;   // == out_size

    // workspace layout: perm (R ints), then 16B-aligned table (R*49 float4)
    size_t perm_bytes  = ((size_t)R * sizeof(int) + 15) & ~(size_t)15;
    size_t table_bytes = (size_t)nbins * sizeof(float4);

    if (perm_bytes + table_bytes <= ws_size) {
        int*    perm  = (int*)d_ws;
        float4* table = (float4*)((char*)d_ws + perm_bytes);

        roi_countsort<<<1, 1024, 0, stream>>>(rois, perm, R);
        roi_precompute<<<(nbins + 255) / 256, 256, 0, stream>>>(rois, table, nbins);

        int workPerGrp   = R * PER_ROI_GRP;            // R*1568
        int blocksPerGrp = (workPerGrp + 255) / 256;
        roi_main<<<blocksPerGrp * NGRP, 256, 0, stream>>>(feat, table, perm, out, R);
    } else {
        roi_fused<<<(total + 255) / 256, 256, 0, stream>>>(feat, rois, out, total);
    }
}

// Round 4
// 98.333 us; speedup vs baseline: 3.1821x; 1.0858x over previous
//
#include <hip/hip_runtime.h>

// RoIAlign: features (B=4, C=256, H=200, W=200) f32, rois (R,5) f32,
// out (R, C, 7, 7) f32.  SCALE=0.25, AH=AW=7, legacy (x2-x1+1) semantics.
//
// Locality plan:
//  - 8 channel-groups of 32ch, block id = j*8 + g so XCD g (round-robin
//    dispatch heuristic) only touches channels [32g,32g+32): per-XCD feature
//    footprint 20.5 MB instead of 164 MB.
//  - ROIs processed in (batch, y-tile, x-tile) sorted order so spatially
//    overlapping ROIs (~11x pixel overlap within a batch) are processed
//    back-to-back: feature-line reuse distance fits in per-XCD L2 (4MB)
//    instead of thrashing to L3.
//  - Output written once via nontemporal stores (keep L2 for features).

#define C_     256
#define H_     200
#define W_     200
#define NBIN   49     // 7*7
#define SCALE_ 0.25f
#define CGRP   32     // channels per XCD group
#define NGRP   8
#define PER_ROI_GRP (CGRP * NBIN)   // 1568 work items per (roi, group)
#define NKEY   256    // 4 batches x 8 y-tiles x 8 x-tiles

// ---------------- kernel 0: locality sort (counting sort, 256 buckets) -----
// key = (batch<<6) | (ytile<<3) | xtile.  Order within a bucket is arbitrary
// (atomics) — output values land at absolute indices, so d_out is
// deterministic regardless of processing order.
__global__ __launch_bounds__(1024) void roi_sortkey(
        const float* __restrict__ rois, int* __restrict__ perm, int R) {
    __shared__ int cnt[NKEY];
    __shared__ int off[NKEY];
    int t = threadIdx.x;
    if (t < NKEY) cnt[t] = 0;
    __syncthreads();
    for (int i = t; i < R; i += 1024) {
        const float* rr = rois + (size_t)i * 5;
        int b = ((int)rr[0]) & 3;
        float xc = (rr[1] + rr[3]) * 0.5f * SCALE_;   // [0,200)
        float yc = (rr[2] + rr[4]) * 0.5f * SCALE_;
        int xt = min(7, max(0, (int)(xc * 0.04f)));   // 25px tiles
        int yt = min(7, max(0, (int)(yc * 0.04f)));
        int key = (b << 6) | (yt << 3) | xt;
        atomicAdd(&cnt[key], 1);
    }
    __syncthreads();
    if (t == 0) {
        int s = 0;
        for (int k = 0; k < NKEY; ++k) { off[k] = s; s += cnt[k]; }
    }
    __syncthreads();
    for (int i = t; i < R; i += 1024) {
        const float* rr = rois + (size_t)i * 5;
        int b = ((int)rr[0]) & 3;
        float xc = (rr[1] + rr[3]) * 0.5f * SCALE_;
        float yc = (rr[2] + rr[4]) * 0.5f * SCALE_;
        int xt = min(7, max(0, (int)(xc * 0.04f)));
        int yt = min(7, max(0, (int)(yc * 0.04f)));
        int key = (b << 6) | (yt << 3) | xt;
        int pos = atomicAdd(&off[key], 1);
        perm[pos] = i;
    }
}

// ---------------- kernel 1: per-(roi,bin) geometry table -------------------
// table[i] = { hr, wr, as_float(h0 | w0<<8 | b<<16 | valid<<18), 0 }
__global__ __launch_bounds__(256) void roi_precompute(
        const float* __restrict__ rois, float4* __restrict__ table, int nbins) {
    int i = blockIdx.x * 256 + threadIdx.x;
    if (i >= nbins) return;
    int r   = i / NBIN;
    int bin = i - r * NBIN;
    int ph  = bin / 7;
    int pw  = bin - ph * 7;

    float bf = rois[r * 5 + 0];
    float x1 = rois[r * 5 + 1] * SCALE_;
    float y1 = rois[r * 5 + 2] * SCALE_;
    float x2 = rois[r * 5 + 3] * SCALE_;
    float y2 = rois[r * 5 + 4] * SCALE_;

    float roi_w = fmaxf(x2 - x1 + 1.0f, 0.0f);
    float roi_h = fmaxf(y2 - y1 + 1.0f, 0.0f);
    float bin_h = roi_h / 6.0f;   // AH-1
    float bin_w = roi_w / 6.0f;   // AW-1

    float h = y1 + (float)ph * bin_h;
    float w = x1 + (float)pw * bin_w;

    bool valid = (h >= 0.0f) && (h < (float)H_) && (w >= 0.0f) && (w < (float)W_);

    float h0f = fmaxf(fminf(floorf(h), (float)(H_ - 2)), 0.0f);
    float w0f = fmaxf(fminf(floorf(w), (float)(W_ - 2)), 0.0f);
    int h0 = (int)h0f;
    int w0 = (int)w0f;
    float hr = h - h0f;
    float wr = w - w0f;
    int b = (int)bf;

    int packed = h0 | (w0 << 8) | (b << 16) | ((valid ? 1 : 0) << 18);
    table[i] = make_float4(hr, wr, __int_as_float(packed), 0.0f);
}

// ---------------- kernel 2: main gather -------------------------------------
// bid = j*8 + g ; group g covers channels [g*32, g*32+32).
// Work item within group: w = (pos*32 + ci)*49 + bin, pos = sorted roi rank.
__global__ __launch_bounds__(256) void roi_main(
        const float* __restrict__ feat, const float4* __restrict__ table,
        const int* __restrict__ perm, float* __restrict__ out, int R) {
    int bid = blockIdx.x;
    int g   = bid & (NGRP - 1);
    int j   = bid >> 3;
    int w   = j * 256 + threadIdx.x;

    int pos = w / PER_ROI_GRP;
    if (pos >= R) return;
    int rem = w - pos * PER_ROI_GRP;
    int ci  = rem / NBIN;
    int bin = rem - ci * NBIN;

    int r = perm[pos];
    int c = g * CGRP + ci;

    float4 t   = table[r * NBIN + bin];
    int packed = __float_as_int(t.z);
    int h0 = packed & 255;
    int w0 = (packed >> 8) & 255;
    int b  = (packed >> 16) & 3;
    float valid = (float)((packed >> 18) & 1);

    const float* p = feat + ((size_t)(b * C_ + c)) * (size_t)(H_ * W_)
                          + (size_t)(h0 * W_ + w0);
    float v00 = p[0];
    float v01 = p[1];
    float v10 = p[W_];
    float v11 = p[W_ + 1];

    float hr = t.x, wr = t.y;
    float top = fmaf(wr, v01 - v00, v00);
    float bot = fmaf(wr, v11 - v10, v10);
    float val = fmaf(hr, bot - top, top);

    int oidx = (r * C_ + c) * NBIN + bin;
    __builtin_nontemporal_store(val * valid, &out[oidx]);
}

// ---------------- fallback: fused (no workspace) ----------------------------
__global__ __launch_bounds__(256) void roi_fused(
        const float* __restrict__ feat, const float* __restrict__ rois,
        float* __restrict__ out, int total) {
    int idx = blockIdx.x * 256 + threadIdx.x;
    if (idx >= total) return;

    unsigned u   = (unsigned)idx;
    unsigned bin = u % (unsigned)NBIN;
    unsigned rc  = u / (unsigned)NBIN;
    unsigned c   = rc & 255u;
    unsigned r   = rc >> 8;
    int ph = bin / 7;
    int pw = bin - ph * 7;

    float bf = rois[r * 5 + 0];
    float x1 = rois[r * 5 + 1] * SCALE_;
    float y1 = rois[r * 5 + 2] * SCALE_;
    float x2 = rois[r * 5 + 3] * SCALE_;
    float y2 = rois[r * 5 + 4] * SCALE_;

    float roi_w = fmaxf(x2 - x1 + 1.0f, 0.0f);
    float roi_h = fmaxf(y2 - y1 + 1.0f, 0.0f);
    float h = y1 + (float)ph * (roi_h / 6.0f);
    float w = x1 + (float)pw * (roi_w / 6.0f);

    float valid = ((h >= 0.0f) && (h < (float)H_) && (w >= 0.0f) && (w < (float)W_))
                      ? 1.0f : 0.0f;

    float h0f = fmaxf(fminf(floorf(h), (float)(H_ - 2)), 0.0f);
    float w0f = fmaxf(fminf(floorf(w), (float)(W_ - 2)), 0.0f);
    int h0 = (int)h0f;
    int w0 = (int)w0f;
    float hr = h - h0f;
    float wr = w - w0f;
    int b = (int)bf;

    const float* p = feat + ((size_t)(b * C_ + (int)c)) * (size_t)(H_ * W_)
                          + (size_t)(h0 * W_ + w0);
    float v00 = p[0];
    float v01 = p[1];
    float v10 = p[W_];
    float v11 = p[W_ + 1];

    float top = fmaf(wr, v01 - v00, v00);
    float bot = fmaf(wr, v11 - v10, v10);
    float val = fmaf(hr, bot - top, top);

    out[idx] = val * valid;
}

extern "C" void kernel_launch(void* const* d_in, const int* in_sizes, int n_in,
                              void* d_out, int out_size, void* d_ws, size_t ws_size,
                              hipStream_t stream) {
    const float* feat = (const float*)d_in[0];
    const float* rois = (const float*)d_in[1];
    float* out = (float*)d_out;

    int R     = in_sizes[1] / 5;
    int nbins = R * NBIN;
    int total = R * C_ * NBIN;   // == out_size

    // workspace layout: perm (R ints), then 16B-aligned table (R*49 float4)
    size_t perm_bytes  = ((size_t)R * sizeof(int) + 15) & ~(size_t)15;
    size_t table_bytes = (size_t)nbins * sizeof(float4);

    if (perm_bytes + table_bytes <= ws_size) {
        int*    perm  = (int*)d_ws;
        float4* table = (float4*)((char*)d_ws + perm_bytes);

        roi_sortkey<<<1, 1024, 0, stream>>>(rois, perm, R);
        roi_precompute<<<(nbins + 255) / 256, 256, 0, stream>>>(rois, table, nbins);

        int workPerGrp   = R * PER_ROI_GRP;            // R*1568
        int blocksPerGrp = (workPerGrp + 255) / 256;
        roi_main<<<blocksPerGrp * NGRP, 256, 0, stream>>>(feat, table, perm, out, R);
    } else {
        roi_fused<<<(total + 255) / 256, 256, 0, stream>>>(feat, rois, out, total);
    }
}